// Round 1
// 4349.405 us; speedup vs baseline: 1.4469x; 1.4469x over previous
//
#include <hip/hip_runtime.h>
#include <math.h>

#define NND   10000
#define FIN   3000
#define HH1   500
#define HH2   64
#define NEDGE 160000

// ---------------- output layout (floats) ----------------
static const size_t OFF_Z1   = 0;
static const size_t OFF_Z2   = 640000;
static const size_t OFF_Z3   = 1280000;
static const size_t OFF_PI   = 1920000;
static const size_t OFF_DISP = 31920000;
static const size_t OFF_MEAN = 61920000;
static const size_t OFF_REC  = 91920000;
static const size_t OFF_RET  = 191920000;

typedef __attribute__((ext_vector_type(8))) short bf16x8;
typedef __attribute__((ext_vector_type(4))) float f32x4;

__device__ __forceinline__ unsigned short f2bf(float x) {
  unsigned int u = __float_as_uint(x);
  u += 0x7FFFu + ((u >> 16) & 1u);      // round-to-nearest-even
  return (unsigned short)(u >> 16);
}

// ---------------- CSR build ----------------
__global__ void k_count(const int* __restrict__ rows, int* __restrict__ cnt) {
  int e = blockIdx.x * 256 + threadIdx.x;
  if (e < NEDGE) atomicAdd(&cnt[rows[e]], 1);
}

__global__ void k_scan(const int* __restrict__ cnt, int* __restrict__ offs,
                       int* __restrict__ cursor) {
  __shared__ int part[256];
  int t = threadIdx.x;
  const int CH = 40;                       // 256*40 = 10240 >= 10000
  int st = t * CH;
  int s = 0;
  for (int i = 0; i < CH; i++) { int idx = st + i; if (idx < NND) s += cnt[idx]; }
  part[t] = s;
  __syncthreads();
  for (int d = 1; d < 256; d <<= 1) {
    int v = (t >= d) ? part[t - d] : 0;
    __syncthreads();
    part[t] += v;
    __syncthreads();
  }
  int run = (t == 0) ? 0 : part[t - 1];
  for (int i = 0; i < CH; i++) {
    int idx = st + i;
    if (idx < NND) { offs[idx] = run; cursor[idx] = run; run += cnt[idx]; }
  }
  if (t == 255) offs[NND] = run;           // == NEDGE
}

__global__ void k_scatter(const int* __restrict__ rows, int* __restrict__ cursor,
                          int* __restrict__ perm) {
  int e = blockIdx.x * 256 + threadIdx.x;
  if (e < NEDGE) { int pos = atomicAdd(&cursor[rows[e]], 1); perm[pos] = e; }
}

// ---------------- epilogues ----------------
template <int EPI>
__device__ __forceinline__ float epi_apply(float v, float b) {
  if (EPI == 0) return v;
  float x = v + b;
  if (EPI == 1) return 1.f / (1.f + __expf(-x));                       // sigmoid
  if (EPI == 2) {                                                      // softplus clip
    float sp = fmaxf(x, 0.f) + log1pf(__expf(-fabsf(x)));
    return fminf(fmaxf(sp, 1e-4f), 1e4f);
  }
  float e = __expf(x);                                                 // exp clip
  return fminf(fmaxf(e, 1e-5f), 1e6f);
}

// ---------------- fp32 tiled GEMM: C[M,N] = A[M,K]*B[K,N] ----------------
// 128x128 tile, BK=16, 256 threads, 8x8 per thread.
// Batched over blockIdx.z by A-pointer select + C stride (for the 3 encoder inputs).
template <int EPI>
__global__ __launch_bounds__(256)
void gemm_tile(const float* __restrict__ A0, const float* __restrict__ A1,
               const float* __restrict__ A2, const float* __restrict__ B,
               float* __restrict__ Cb, size_t cstride,
               const float* __restrict__ bias, int M, int Nn, int K) {
  __shared__ float As[16][128];   // [k][m]
  __shared__ float Bs[16][128];   // [k][n]
  const int z = blockIdx.z;
  const float* A = (z == 0) ? A0 : ((z == 1) ? A1 : A2);
  float* C = Cb + (size_t)z * cstride;
  const int t  = threadIdx.x;
  const int tx = t & 15;          // col group: cols {tx*4..+3} and {64+tx*4..+3}
  const int ty = t >> 4;          // row group: rows ty*8..+7
  const int bm = blockIdx.x * 128;
  const int bn = blockIdx.y * 128;

  float acc[8][8];
  #pragma unroll
  for (int i = 0; i < 8; i++)
    #pragma unroll
    for (int j = 0; j < 8; j++) acc[i][j] = 0.f;

  for (int k0 = 0; k0 < K; k0 += 16) {
    // A tile: 128 rows x 16 k, stored transposed As[k][m]
    #pragma unroll
    for (int i = 0; i < 2; i++) {
      int id  = t * 2 + i;          // 0..511
      int row = id >> 2;            // 0..127
      int kk  = (id & 3) * 4;       // 0,4,8,12
      int gr  = bm + row;
      int gk  = k0 + kk;
      float4 v = make_float4(0.f, 0.f, 0.f, 0.f);
      if (gr < M) {
        if (gk + 3 < K) {
          v = *(const float4*)(A + (size_t)gr * K + gk);
        } else {
          float tmp[4] = {0.f, 0.f, 0.f, 0.f};
          #pragma unroll
          for (int c = 0; c < 4; c++)
            if (gk + c < K) tmp[c] = A[(size_t)gr * K + gk + c];
          v = make_float4(tmp[0], tmp[1], tmp[2], tmp[3]);
        }
      }
      As[kk + 0][row] = v.x; As[kk + 1][row] = v.y;
      As[kk + 2][row] = v.z; As[kk + 3][row] = v.w;
    }
    // B tile: 16 k x 128 n
    #pragma unroll
    for (int i = 0; i < 2; i++) {
      int id = t * 2 + i;
      int kk = id >> 5;             // 0..15
      int n4 = (id & 31) * 4;       // 0..124
      int gk = k0 + kk;
      int gn = bn + n4;
      float4 v = make_float4(0.f, 0.f, 0.f, 0.f);
      if (gk < K) {
        if (gn + 3 < Nn) {
          v = *(const float4*)(B + (size_t)gk * Nn + gn);
        } else {
          float tmp[4] = {0.f, 0.f, 0.f, 0.f};
          #pragma unroll
          for (int c = 0; c < 4; c++)
            if (gn + c < Nn) tmp[c] = B[(size_t)gk * Nn + gn + c];
          v = make_float4(tmp[0], tmp[1], tmp[2], tmp[3]);
        }
      }
      *(float4*)&Bs[kk][n4] = v;
    }
    __syncthreads();
    #pragma unroll
    for (int kk = 0; kk < 16; kk++) {
      float a[8], b[8];
      *(float4*)&a[0] = *(const float4*)&As[kk][ty * 8];
      *(float4*)&a[4] = *(const float4*)&As[kk][ty * 8 + 4];
      *(float4*)&b[0] = *(const float4*)&Bs[kk][tx * 4];
      *(float4*)&b[4] = *(const float4*)&Bs[kk][64 + tx * 4];
      #pragma unroll
      for (int i = 0; i < 8; i++)
        #pragma unroll
        for (int j = 0; j < 8; j++) acc[i][j] += a[i] * b[j];
    }
    __syncthreads();
  }
  // epilogue: coalesced float4 stores (cols bn+h*64+tx*4)
  #pragma unroll
  for (int i = 0; i < 8; i++) {
    int gr = bm + ty * 8 + i;
    if (gr >= M) continue;
    float* crow = C + (size_t)gr * Nn;
    #pragma unroll
    for (int h = 0; h < 2; h++) {
      int gn0 = bn + h * 64 + tx * 4;
      if (gn0 + 3 < Nn) {
        float4 o;
        o.x = epi_apply<EPI>(acc[i][h * 4 + 0], EPI ? bias[gn0 + 0] : 0.f);
        o.y = epi_apply<EPI>(acc[i][h * 4 + 1], EPI ? bias[gn0 + 1] : 0.f);
        o.z = epi_apply<EPI>(acc[i][h * 4 + 2], EPI ? bias[gn0 + 2] : 0.f);
        o.w = epi_apply<EPI>(acc[i][h * 4 + 3], EPI ? bias[gn0 + 3] : 0.f);
        *(float4*)(crow + gn0) = o;
      } else {
        #pragma unroll
        for (int j = 0; j < 4; j++) {
          int gn = gn0 + j;
          if (gn < Nn) crow[gn] = epi_apply<EPI>(acc[i][h * 4 + j], EPI ? bias[gn] : 0.f);
        }
      }
    }
  }
}

// ---------------- CSR aggregation: out[r,:] = sum_e val[e]*sup[col[e],:] ----------------
template <int H, int NT, bool RELU>
__global__ void agg_csr(const float* __restrict__ supB, size_t sstride,
                        float* __restrict__ outB, size_t ostride,
                        const int* __restrict__ offs, const int* __restrict__ perm,
                        const int* __restrict__ cols, const float* __restrict__ vals) {
  const int z = blockIdx.z;
  const float* sup = supB + (size_t)z * sstride;
  float* out = outB + (size_t)z * ostride;
  const int r = blockIdx.x;
  const int t = threadIdx.x;
  constexpr int PJ = (H + NT - 1) / NT;
  float acc[PJ];
  #pragma unroll
  for (int j = 0; j < PJ; j++) acc[j] = 0.f;
  const int b = offs[r], e = offs[r + 1];
  for (int i = b; i < e; i++) {
    int ed = perm[i];
    int c  = cols[ed];
    float v = vals[ed];
    #pragma unroll
    for (int j = 0; j < PJ; j++) {
      int col = t + j * NT;
      if (col < H) acc[j] += v * sup[(size_t)c * H + col];
    }
  }
  #pragma unroll
  for (int j = 0; j < PJ; j++) {
    int col = t + j * NT;
    if (col < H) out[(size_t)r * H + col] = RELU ? fmaxf(acc[j], 0.f) : acc[j];
  }
}

// ---------------- small elementwise / row kernels ----------------
__global__ void k_relu2(const float* __restrict__ a, const float* __restrict__ b,
                        float* __restrict__ ea, float* __restrict__ eb, int n) {
  int i = blockIdx.x * 256 + threadIdx.x;
  if (i < n) { ea[i] = fmaxf(a[i], 0.f); eb[i] = fmaxf(b[i], 0.f); }
}

__global__ void k_l2norm(const float* __restrict__ x, float* __restrict__ y) {
  int n = blockIdx.x, t = threadIdx.x;  // 64 threads
  float v = x[(size_t)n * 64 + t];
  float s = v * v;
  #pragma unroll
  for (int m = 32; m >= 1; m >>= 1) s += __shfl_xor(s, m, 64);
  y[(size_t)n * 64 + t] = v / fmaxf(sqrtf(s), 1e-12f);
}

__global__ void k_readout_norm(float* __restrict__ vs, const float* __restrict__ rs) {
  int n = blockIdx.x, t = threadIdx.x;  // 64 threads; in-place vsum -> g2
  float v = vs[(size_t)n * 64 + t] / rs[n];
  float s = v * v;
  #pragma unroll
  for (int m = 32; m >= 1; m >>= 1) s += __shfl_xor(s, m, 64);
  v = v / fmaxf(sqrtf(s), 1e-12f);
  vs[(size_t)n * 64 + t] = 1.f / (1.f + __expf(-v));
}

__global__ void k_disc(const float* __restrict__ emb1, const float* __restrict__ emb3,
                       const float* __restrict__ g2, const float* __restrict__ W,
                       const float* __restrict__ bptr, float* __restrict__ ret) {
  __shared__ float sh[64];
  int n = blockIdx.x, t = threadIdx.x;  // 64 threads
  sh[t] = g2[(size_t)n * 64 + t];
  __syncthreads();
  float td = 0.f;
  #pragma unroll
  for (int e = 0; e < 64; e++) td += W[t * 64 + e] * sh[e];
  float s1 = emb1[(size_t)n * 64 + t] * td;
  float s2 = emb3[(size_t)n * 64 + t] * td;
  #pragma unroll
  for (int m = 32; m >= 1; m >>= 1) { s1 += __shfl_xor(s1, m, 64); s2 += __shfl_xor(s2, m, 64); }
  if (t == 0) { float b = bptr[0]; ret[n * 2 + 0] = s1 + b; ret[n * 2 + 1] = s2 + b; }
}

// ---------------- xd = relu(bn(z1 @ Wd + bd)) ----------------
__global__ __launch_bounds__(128)
void k_xd(const float* __restrict__ z1, const float* __restrict__ Wd,
          const float* __restrict__ bd, const float* __restrict__ gam,
          const float* __restrict__ bet, const float* __restrict__ mu,
          const float* __restrict__ var, float* __restrict__ xd) {
  __shared__ float Ws[64][128];
  __shared__ float Zs[16][64];
  const int r0 = blockIdx.x * 16;
  const int bj = blockIdx.y * 128;
  const int t  = threadIdx.x;
  for (int k = 0; k < 64; k++) {
    int j = bj + t;
    Ws[k][t] = (j < HH1) ? Wd[k * HH1 + j] : 0.f;
  }
  #pragma unroll
  for (int i = 0; i < 8; i++) {
    int idx = t + 128 * i;          // 0..1023
    int rr = idx >> 6, k = idx & 63;
    int gr = r0 + rr;
    Zs[rr][k] = (gr < NND) ? z1[(size_t)gr * 64 + k] : 0.f;
  }
  __syncthreads();
  int j = bj + t;
  if (j < HH1) {
    float g = gam[j], bb = bet[j], m = mu[j], iv = rsqrtf(var[j] + 1e-5f), b0 = bd[j];
    for (int rr = 0; rr < 16; rr++) {
      int gr = r0 + rr;
      if (gr >= NND) break;
      float acc = b0;
      #pragma unroll
      for (int k = 0; k < 64; k++) acc += Zs[rr][k] * Ws[k][t];
      float h = g * (acc - m) * iv + bb;
      xd[(size_t)gr * HH1 + j] = fmaxf(h, 0.f);
    }
  }
}

// ---------------- rec_adj = sigmoid(zn @ zn^T), 128x128 tiles, K=64 ----------------
__global__ __launch_bounds__(256)
void k_recadj(const float* __restrict__ zn, float* __restrict__ out) {
  __shared__ float Za[32][132];
  __shared__ float Zb[32][132];
  const int bm = blockIdx.x * 128;
  const int bn = blockIdx.y * 128;
  const int t  = threadIdx.x;
  const int tx = t & 15, ty = t >> 4;
  float acc[8][8];
  #pragma unroll
  for (int i = 0; i < 8; i++)
    #pragma unroll
    for (int j = 0; j < 8; j++) acc[i][j] = 0.f;

  for (int kp = 0; kp < 2; kp++) {
    int k0 = kp * 32;
    #pragma unroll
    for (int i = 0; i < 4; i++) {
      int idx = t + 256 * i;        // 0..1023
      int row = idx >> 3;           // 0..127
      int kq  = (idx & 7) * 4;      // 0..28
      int gr = bm + row;
      float4 v = (gr < NND) ? *(const float4*)(zn + (size_t)gr * 64 + k0 + kq)
                            : make_float4(0.f, 0.f, 0.f, 0.f);
      Za[kq + 0][row] = v.x; Za[kq + 1][row] = v.y;
      Za[kq + 2][row] = v.z; Za[kq + 3][row] = v.w;
      int gc = bn + row;
      float4 w = (gc < NND) ? *(const float4*)(zn + (size_t)gc * 64 + k0 + kq)
                            : make_float4(0.f, 0.f, 0.f, 0.f);
      Zb[kq + 0][row] = w.x; Zb[kq + 1][row] = w.y;
      Zb[kq + 2][row] = w.z; Zb[kq + 3][row] = w.w;
    }
    __syncthreads();
    #pragma unroll
    for (int kk = 0; kk < 32; kk++) {
      float a[8], b[8];
      *(float4*)&a[0] = *(const float4*)&Za[kk][ty * 8];
      *(float4*)&a[4] = *(const float4*)&Za[kk][ty * 8 + 4];
      *(float4*)&b[0] = *(const float4*)&Zb[kk][tx * 4];
      *(float4*)&b[4] = *(const float4*)&Zb[kk][64 + tx * 4];
      #pragma unroll
      for (int i = 0; i < 8; i++)
        #pragma unroll
        for (int j = 0; j < 8; j++) acc[i][j] += a[i] * b[j];
    }
    __syncthreads();
  }
  #pragma unroll
  for (int i = 0; i < 8; i++) {
    int gr = bm + ty * 8 + i;
    if (gr >= NND) continue;
    float* crow = out + (size_t)gr * NND;
    #pragma unroll
    for (int h = 0; h < 2; h++) {
      int gn0 = bn + h * 64 + tx * 4;
      if (gn0 + 3 < NND) {
        float4 o;
        o.x = 1.f / (1.f + __expf(-acc[i][h * 4 + 0]));
        o.y = 1.f / (1.f + __expf(-acc[i][h * 4 + 1]));
        o.z = 1.f / (1.f + __expf(-acc[i][h * 4 + 2]));
        o.w = 1.f / (1.f + __expf(-acc[i][h * 4 + 3]));
        *(float4*)(crow + gn0) = o;
      } else {
        #pragma unroll
        for (int j = 0; j < 4; j++) {
          int gn = gn0 + j;
          if (gn < NND) crow[gn] = 1.f / (1.f + __expf(-acc[i][h * 4 + j]));
        }
      }
    }
  }
}

// ---------------- emb1 -> ET bf16 transposed [64][NND] ----------------
__global__ __launch_bounds__(256)
void k_e_to_bf16t(const float* __restrict__ emb, unsigned short* __restrict__ ET) {
  __shared__ float Ts[64][65];
  const int r0 = blockIdx.x * 64;
  const int t  = threadIdx.x;
  #pragma unroll
  for (int i = 0; i < 4; i++) {
    int f = t + 256 * i;            // 0..1023 float4 slots
    int row = f >> 4;               // 0..63
    int c4  = (f & 15) * 4;         // 0..60
    int gr = r0 + row;
    float4 v = make_float4(0.f, 0.f, 0.f, 0.f);
    if (gr < NND) v = *(const float4*)(emb + (size_t)gr * 64 + c4);
    Ts[row][c4 + 0] = v.x; Ts[row][c4 + 1] = v.y;
    Ts[row][c4 + 2] = v.z; Ts[row][c4 + 3] = v.w;
  }
  __syncthreads();
  #pragma unroll
  for (int i = 0; i < 16; i++) {
    int f = t + 256 * i;            // 0..4095
    int c = f >> 6;                 // 0..63 (column of emb)
    int r = f & 63;                 // 0..63 (row within tile)
    int gr = r0 + r;
    if (gr < NND) ET[(size_t)c * NND + gr] = f2bf(Ts[r][c]);
  }
}

// ---------------- readout GEMM: vsum += G[r0:+64, kbeg:kend] @ E ; rowsum += G @ 1 ----
// bf16 MFMA 16x16x32; A staged fp32->bf16 in swizzled LDS; B read from ET (L2-resident).
#define KSPLIT 4
__global__ __launch_bounds__(256)
void k_readout_mfma(const float* __restrict__ g, const unsigned short* __restrict__ ET,
                    float* __restrict__ vsum, float* __restrict__ rowsum) {
  __shared__ unsigned short As[64 * 64];            // 8 KB, XOR-swizzled
  const int r0   = blockIdx.x * 64;
  const int kbeg = blockIdx.y * (NND / KSPLIT);
  const int kend = kbeg + (NND / KSPLIT);
  const int t    = threadIdx.x;
  const int lane = t & 63;
  const int w    = t >> 6;                          // wave id, owns rows w*16..+15
  const int l15  = lane & 15;
  const int kgrp = (lane >> 4) << 3;                // 0,8,16,24 (k sub-offset)
  const int arow = (w << 4) + l15;                  // A row this lane reads

  f32x4 acc[4];
  #pragma unroll
  for (int ct = 0; ct < 4; ct++)
    #pragma unroll
    for (int j = 0; j < 4; j++) acc[ct][j] = 0.f;
  float rs[4] = {0.f, 0.f, 0.f, 0.f};

  char* Ab = (char*)As;
  for (int k0 = kbeg; k0 < kend; k0 += 64) {
    // stage A tile: 64 rows x 64 k, fp32 -> bf16, swizzled (byte ^= (row&7)<<4)
    #pragma unroll
    for (int i = 0; i < 4; i++) {
      int f   = t + 256 * i;        // 0..1023 float4 slots
      int row = f >> 4;             // 0..63
      int c4  = (f & 15) << 2;      // 0..60
      int gr  = r0 + row;
      int gk  = k0 + c4;
      float4 v = make_float4(0.f, 0.f, 0.f, 0.f);
      if (gr < NND && gk < kend) v = *(const float4*)(g + (size_t)gr * NND + gk);
      rs[i] += v.x + v.y + v.z + v.w;
      unsigned int lo = (unsigned int)f2bf(v.x) | ((unsigned int)f2bf(v.y) << 16);
      unsigned int hi = (unsigned int)f2bf(v.z) | ((unsigned int)f2bf(v.w) << 16);
      int boff = ((row << 7) + (c4 << 1)) ^ ((row & 7) << 4);
      *(uint2*)(Ab + boff) = make_uint2(lo, hi);
    }
    __syncthreads();
    #pragma unroll
    for (int ks = 0; ks < 2; ks++) {
      int aoff = ((arow << 7) + ((kgrp + ks * 32) << 1)) ^ ((arow & 7) << 4);
      bf16x8 a = *(const bf16x8*)(Ab + aoff);
      int gk = k0 + ks * 32 + kgrp;                 // B k-base for this lane
      gk = (gk <= NND - 8) ? gk : (NND - 8);        // clamp: A is zero there anyway
      #pragma unroll
      for (int ct = 0; ct < 4; ct++) {
        int bcol = (ct << 4) + l15;
        bf16x8 b = *(const bf16x8*)(ET + (size_t)bcol * NND + gk);
        acc[ct] = __builtin_amdgcn_mfma_f32_16x16x32_bf16(a, b, acc[ct], 0, 0, 0);
      }
    }
    __syncthreads();
  }
  // store D: row = (lane>>4)*4 + j, col = ct*16 + (lane&15)   [C/D layout, m89-verified]
  #pragma unroll
  for (int ct = 0; ct < 4; ct++) {
    #pragma unroll
    for (int j = 0; j < 4; j++) {
      int gr = r0 + (w << 4) + ((lane >> 4) << 2) + j;
      int col = (ct << 4) + l15;
      if (gr < NND) atomicAdd(&vsum[(size_t)gr * 64 + col], acc[ct][j]);
    }
  }
  // rowsum: thread's slot i covers fixed row (t+256i)>>4; reduce 16 contributions/row
  float* RS = (float*)As;                           // reuse LDS (4 KB of 8)
  #pragma unroll
  for (int i = 0; i < 4; i++) RS[i * 256 + t] = rs[i];
  __syncthreads();
  if (t < 64) {
    int base = (t >> 4) * 256 + ((t & 15) << 4);
    float s = 0.f;
    #pragma unroll
    for (int q = 0; q < 16; q++) s += RS[base + q];
    int gr = r0 + t;
    if (gr < NND) atomicAdd(&rowsum[gr], s);
  }
}

// ---------------- host launcher ----------------
extern "C" void kernel_launch(void* const* d_in, const int* in_sizes, int n_in,
                              void* d_out, int out_size, void* d_ws, size_t ws_size,
                              hipStream_t stream) {
  (void)in_sizes; (void)n_in; (void)out_size; (void)ws_size;
  const float* feat   = (const float*)d_in[0];
  const float* feat_a = (const float*)d_in[1];
  const float* feat_b = (const float*)d_in[2];
  const int*   rows   = (const int*)d_in[3];
  const int*   colsA  = (const int*)d_in[4];
  const float* vals   = (const float*)d_in[5];
  const float* graph  = (const float*)d_in[6];
  const float* W1     = (const float*)d_in[7];
  const float* W2     = (const float*)d_in[8];
  const float* Wd     = (const float*)d_in[9];
  const float* bd     = (const float*)d_in[10];
  const float* gam    = (const float*)d_in[11];
  const float* bet    = (const float*)d_in[12];
  const float* bmu    = (const float*)d_in[13];
  const float* bvar   = (const float*)d_in[14];
  const float* Wpi    = (const float*)d_in[15];
  const float* bpi    = (const float*)d_in[16];
  const float* Wdisp  = (const float*)d_in[17];
  const float* bdis   = (const float*)d_in[18];
  const float* Wmean  = (const float*)d_in[19];
  const float* bmean  = (const float*)d_in[20];
  const float* discW  = (const float*)d_in[21];
  const float* discb  = (const float*)d_in[22];
  float* out = (float*)d_out;

  // workspace layout (~140 MB)
  float* S1   = (float*)d_ws;            // 3 x 5,000,000 (xd reuses slot 0 later)
  float* Hb   = S1 + 15000000;           // 3 x 5,000,000
  float* S2   = Hb + 15000000;           // 3 x 640,000
  float* emb1 = S2 + 1920000;            // 640,000
  float* emb3 = emb1 + 640000;           // 640,000
  float* znb  = emb3 + 640000;           // 640,000
  float* g2b  = znb + 640000;            // 640,000 (vsum -> g2 in place)
  float* rsum = g2b + 640000;            // 10,000 (+pad)
  int*   cnt    = (int*)(rsum + 10016);  // 10,000 (+pad)
  int*   offs   = cnt + 10016;           // 10,001 (+pad)
  int*   cursor = offs + 10016;          // 10,000 (+pad)
  int*   perm   = cursor + 10016;        // 160,000
  // ET bf16 [64][NND] lives in the free upper part of S1 (encoders done, xd uses
  // only S1[0:5e6]): byte offset 20 MB, 16B-aligned.
  unsigned short* ETb = (unsigned short*)(S1 + 5000000);   // 640,000 ushorts

  const int GM = (NND + 127) / 128;      // 79
  const int GT = (NND + 63) / 64;        // 157

  // --- CSR build (same adjacency reused by both conv layers, all 3 encodes) ---
  hipMemsetAsync(cnt, 0, NND * sizeof(int), stream);
  k_count<<<(NEDGE + 255) / 256, 256, 0, stream>>>(rows, cnt);
  k_scan<<<1, 256, 0, stream>>>(cnt, offs, cursor);
  k_scatter<<<(NEDGE + 255) / 256, 256, 0, stream>>>(rows, cursor, perm);

  // --- 3x encoder, batched over blockIdx.z ---
  dim3 gC1(GM, (HH1 + 127) / 128, 3);
  gemm_tile<0><<<gC1, 256, 0, stream>>>(feat, feat_a, feat_b, W1, S1, 5000000,
                                        nullptr, NND, HH1, FIN);
  agg_csr<HH1, 128, true><<<dim3(NND, 1, 3), 128, 0, stream>>>(
      S1, 5000000, Hb, 5000000, offs, perm, colsA, vals);
  dim3 gC2(GM, 1, 3);
  gemm_tile<0><<<gC2, 256, 0, stream>>>(Hb, Hb + 5000000, Hb + 10000000, W2, S2, 640000,
                                        nullptr, NND, HH2, HH1);
  agg_csr<HH2, 64, false><<<dim3(NND, 1, 3), 64, 0, stream>>>(
      S2, 640000, out + OFF_Z1, 640000, offs, perm, colsA, vals);

  const float* z1 = out + OFF_Z1;
  const float* z3 = out + OFF_Z3;

  // --- emb1 = relu(z1), emb3 = relu(z3); zn = l2norm(z1) ---
  k_relu2<<<(640000 + 255) / 256, 256, 0, stream>>>(z1, z3, emb1, emb3, 640000);
  k_l2norm<<<NND, 64, 0, stream>>>(z1, znb);
  k_e_to_bf16t<<<GT, 256, 0, stream>>>(emb1, ETb);

  // --- ZINB decoder ---
  float* xd = S1;   // reuse (encoders are done with S1)
  k_xd<<<dim3(NND / 16, 4), 128, 0, stream>>>(z1, Wd, bd, gam, bet, bmu, bvar, xd);
  dim3 gHead(GM, (FIN + 127) / 128, 1);
  gemm_tile<1><<<gHead, 256, 0, stream>>>(xd, xd, xd, Wpi, out + OFF_PI, 0,
                                          bpi, NND, FIN, HH1);
  gemm_tile<2><<<gHead, 256, 0, stream>>>(xd, xd, xd, Wdisp, out + OFF_DISP, 0,
                                          bdis, NND, FIN, HH1);
  gemm_tile<3><<<gHead, 256, 0, stream>>>(xd, xd, xd, Wmean, out + OFF_MEAN, 0,
                                          bmean, NND, FIN, HH1);

  // --- rec_adj = sigmoid(zn zn^T) ---
  k_recadj<<<dim3(GM, GM), 256, 0, stream>>>(znb, out + OFF_REC);

  // --- readout (MFMA) + discriminator ---
  hipMemsetAsync(g2b, 0, 640000 * sizeof(float), stream);
  hipMemsetAsync(rsum, 0, NND * sizeof(float), stream);
  k_readout_mfma<<<dim3(GT, KSPLIT), 256, 0, stream>>>(graph, ETb, g2b, rsum);
  k_readout_norm<<<NND, 64, 0, stream>>>(g2b, rsum);
  k_disc<<<NND, 64, 0, stream>>>(emb1, emb3, g2b, discW, discb, out + OFF_RET);
}